// Round 7
// baseline (584.274 us; speedup 1.0000x reference)
//
#include <hip/hip_runtime.h>
#include <hip/hip_bf16.h>
#include <stdint.h>
#include <stddef.h>

typedef unsigned short ushort_t;
typedef unsigned int uint_t;

typedef __attribute__((ext_vector_type(8))) short short8;
typedef __attribute__((ext_vector_type(4))) float floatx4;
typedef __attribute__((ext_vector_type(4))) uint_t uintx4;

#define N_ROWS 32768
#define K_ENT  8192
#define CDIM   256
#define OUT_ELEMS 8388608
#define LOSS_OFF  8388608
#define IDX_OFF   8388609
#define SURV_CAP  32
// Screen margin vs per-k-quarter FINAL max: covers bf16 rounding of z,c
// (aligned-worst ~5e-5 each side) + reference fp32 quantization ulp(256)=3.05e-5.
// Survivors ~1-3 per k-quarter => ~4-10 per row total (cap 32 safe).
#define MARGIN    2.0e-4f

// RNE float -> bf16 bits
__device__ __forceinline__ ushort_t f2bf(float f) {
    uint_t x = __float_as_uint(f);
    uint_t r = (x + 0x7fffu + ((x >> 16) & 1u)) >> 16;
    return (ushort_t)r;
}

// Swizzled layout: element (row, c) lives at
//   (row>>4)*4096 + (c>>5)*512 + ((c>>3)&3)*128 + (row&15)*8 + (c&7)   [ushort index]
// -> a wave's MFMA fragment load (lane l: row16=(l&15), c-off (l>>4)*8, 16 B) is
// one contiguous 1 KiB per (rowgroup, cc); a 16-ent codebook entgroup is 8 KB
// contiguous; a 32-ent kt tile is 16 KB contiguous.

// codebook fp32 -> swizzled bf16, fused with cnt/cnt2/acc init
__global__ __launch_bounds__(256) void k_conv_cb(const float* __restrict__ cb,
                                                 ushort_t* __restrict__ cbsw,
                                                 int* __restrict__ cnt,
                                                 int* __restrict__ cnt2,
                                                 double* __restrict__ acc) {
    int t = blockIdx.x * 256 + threadIdx.x;   // 262,144 threads: (ent, c-chunk of 8)
    if (t < N_ROWS) cnt[t] = 0;
    if (t == 0) { *acc = 0.0; *cnt2 = 0; }
    int ent = t >> 5;
    int c0  = (t & 31) << 3;
    const float* p = cb + (size_t)ent * CDIM + c0;
    floatx4 f0 = *(const floatx4*)p;
    floatx4 f1 = *(const floatx4*)(p + 4);
    uintx4 pk;
    pk[0] = (uint_t)f2bf(f0[0]) | ((uint_t)f2bf(f0[1]) << 16);
    pk[1] = (uint_t)f2bf(f0[2]) | ((uint_t)f2bf(f0[3]) << 16);
    pk[2] = (uint_t)f2bf(f1[0]) | ((uint_t)f2bf(f1[1]) << 16);
    pk[3] = (uint_t)f2bf(f1[2]) | ((uint_t)f2bf(f1[3]) << 16);
    int idx = (ent >> 4) * 4096 + (c0 >> 5) * 512 + ((c0 >> 3) & 3) * 128 + (ent & 15) * 8;
    *(uintx4*)(cbsw + idx) = pk;
}

// z[b][c][s] -> swizzled bf16 z_flat[n=b*4096+s][c] (+ optional fp32 transposed copy)
__global__ __launch_bounds__(256) void k_conv_z(const float* __restrict__ zin,
                                                ushort_t* __restrict__ zsw,
                                                float* __restrict__ ztf) {
    __shared__ float lds[64][65];
    int bid = blockIdx.x;
    int c0 = (bid & 3) << 6;
    int s0 = ((bid >> 2) & 63) << 6;
    int b  = bid >> 8;
    int tid = threadIdx.x;
    int j = tid & 63, ib = tid >> 6;
    const float* zb = zin + ((size_t)b << 20);
#pragma unroll
    for (int rr = 0; rr < 16; ++rr) {
        int i = rr * 4 + ib;                       // c-local
        lds[i][j] = zb[(size_t)(c0 + i) * 4096 + s0 + j];   // coalesced over j
    }
    __syncthreads();
#pragma unroll
    for (int it = 0; it < 2; ++it) {
        int item = it * 256 + tid;                 // 512 items: (s-local, c-chunk)
        int sl = item >> 3;
        int ch = item & 7;
        int row = (b << 12) + s0 + sl;             // n
        int cg  = c0 + ch * 8;
        uintx4 pk;
        floatx4 f0, f1;
#pragma unroll
        for (int q = 0; q < 4; ++q) {
            float a = lds[ch * 8 + 2 * q][sl];
            float bqv = lds[ch * 8 + 2 * q + 1][sl];
            pk[q] = (uint_t)f2bf(a) | ((uint_t)f2bf(bqv) << 16);
        }
#pragma unroll
        for (int q = 0; q < 4; ++q) {
            f0[q] = lds[ch * 8 + q][sl];
            f1[q] = lds[ch * 8 + 4 + q][sl];
        }
        int idx = (row >> 4) * 4096 + (cg >> 5) * 512 + ((cg >> 3) & 3) * 128 + (row & 15) * 8;
        *(uintx4*)(zsw + idx) = pk;
        if (ztf) {
            *(floatx4*)(ztf + (size_t)row * 256 + cg) = f0;
            *(floatx4*)(ztf + (size_t)row * 256 + cg + 4) = f1;
        }
    }
}

// Two-phase bf16 MFMA screen, 4 waves/SIMD (round-6 post-mortem: 1 wave/SIMD=16%,
// 2 waves/SIMD=40% MfmaUtil on BOTH the L1 and LDS B-paths -> wave-level latency
// hiding is the limiter, and r5/r6 were grid/LDS-capped at 8 waves/CU).
// Block = 256 thr = 4 waves = 128 rows (R=32/wave, afr[2][8]=64 VGPR -> ~116 total,
// 4 waves/SIMD); each block sweeps one K-QUARTER (2048 ents) in 32-ent LDS tiles,
// double-buffered (2x16 KB -> 32 KB/block -> 4 blocks/CU = 16 waves/CU). Rows are
// unique per wave -> per-wave register thresholds, no cross-wave combine. 4
// independent blocks/CU decouple the per-kt barriers (overlap across blocks).
// Phase A: final per-(row,quarter) max. Phase B: append every k within MARGIN.
__global__ __launch_bounds__(256, 4) void k_screen(const ushort_t* __restrict__ zsw,
                                                   const ushort_t* __restrict__ cbsw,
                                                   int* __restrict__ surv,
                                                   int* __restrict__ cnt) {
    __shared__ ushort_t bt[2][8192];    // 2 x 16 KB B tiles (32 ents each)
    int tid = threadIdx.x;              // 0..255
    int w = tid >> 6, l = tid & 63;
    int lo8 = l * 8;
    int g = l >> 4, e = l & 15;
    int bid = blockIdx.x;
    int q  = bid & 3;                   // k-quarter
    int RB = (bid >> 2) * 128;          // row base; wave w owns rows [RB+w*32, +32)
    int egbase = q * 128;               // first entgroup of this quarter

    short8 afr[2][8];
#pragma unroll
    for (int m = 0; m < 2; ++m) {
        const ushort_t* pa = zsw + (size_t)((RB >> 4) + w * 2 + m) * 4096 + lo8;
#pragma unroll
        for (int cc = 0; cc < 8; ++cc)
            afr[m][cc] = *(const short8*)(pa + cc * 512);
    }

    float rmx[2][4];
#pragma unroll
    for (int m = 0; m < 2; ++m)
#pragma unroll
        for (int r = 0; r < 4; ++r) rmx[m][r] = -3.0e38f;

    uintx4 pf[4];
    // prologue: stage tile 0 into buf 0 (tile = 16 KB = 1024 uintx4; 4/thread)
    {
        const uintx4* gsrc = (const uintx4*)(cbsw + (size_t)egbase * 4096);
#pragma unroll
        for (int j = 0; j < 4; ++j) pf[j] = gsrc[j * 256 + tid];
#pragma unroll
        for (int j = 0; j < 4; ++j)
            *(uintx4*)(&bt[0][(j * 256 + tid) * 8]) = pf[j];
    }
    __syncthreads();

    // ---- Phase A: max only ----
    for (int kt = 0; kt < 64; ++kt) {
        int nkt = (kt + 1) & 63;        // kt=63 preloads tile 0 for phase B
        const uintx4* gsrc = (const uintx4*)(cbsw + (size_t)(egbase + nkt * 2) * 4096);
#pragma unroll
        for (int j = 0; j < 4; ++j) pf[j] = gsrc[j * 256 + tid];

        const ushort_t* bb = &bt[kt & 1][lo8];
        floatx4 acc[2][2];
#pragma unroll
        for (int m = 0; m < 2; ++m) {
            acc[m][0] = (floatx4){0.f, 0.f, 0.f, 0.f};
            acc[m][1] = (floatx4){0.f, 0.f, 0.f, 0.f};
        }
#pragma unroll
        for (int cc = 0; cc < 8; ++cc) {
            short8 b0 = *(const short8*)(bb + cc * 512);
            short8 b1 = *(const short8*)(bb + 4096 + cc * 512);
#pragma unroll
            for (int m = 0; m < 2; ++m) {
                acc[m][0] = __builtin_amdgcn_mfma_f32_16x16x32_bf16(afr[m][cc], b0, acc[m][0], 0, 0, 0);
                acc[m][1] = __builtin_amdgcn_mfma_f32_16x16x32_bf16(afr[m][cc], b1, acc[m][1], 0, 0, 0);
            }
        }
#pragma unroll
        for (int m = 0; m < 2; ++m)
#pragma unroll
            for (int r = 0; r < 4; ++r)
                rmx[m][r] = fmaxf(rmx[m][r], fmaxf(acc[m][0][r], acc[m][1][r]));

#pragma unroll
        for (int j = 0; j < 4; ++j)
            *(uintx4*)(&bt[(kt + 1) & 1][(j * 256 + tid) * 8]) = pf[j];
        __syncthreads();
    }

    // reduce over the 16-lane e-group (rows are wave-private, no LDS combine)
    float thr[2][4];
#pragma unroll
    for (int m = 0; m < 2; ++m)
#pragma unroll
        for (int r = 0; r < 4; ++r) {
            float mx = rmx[m][r];
            mx = fmaxf(mx, __shfl_xor(mx, 1));
            mx = fmaxf(mx, __shfl_xor(mx, 2));
            mx = fmaxf(mx, __shfl_xor(mx, 4));
            mx = fmaxf(mx, __shfl_xor(mx, 8));
            thr[m][r] = mx - MARGIN;
        }

    // ---- Phase B: append vs final-quarter-max threshold ----
    for (int kt = 0; kt < 64; ++kt) {
        int nkt = (kt + 1) & 63;
        const uintx4* gsrc = (const uintx4*)(cbsw + (size_t)(egbase + nkt * 2) * 4096);
#pragma unroll
        for (int j = 0; j < 4; ++j) pf[j] = gsrc[j * 256 + tid];

        const ushort_t* bb = &bt[kt & 1][lo8];
        floatx4 acc[2][2];
#pragma unroll
        for (int m = 0; m < 2; ++m) {
            acc[m][0] = (floatx4){0.f, 0.f, 0.f, 0.f};
            acc[m][1] = (floatx4){0.f, 0.f, 0.f, 0.f};
        }
#pragma unroll
        for (int cc = 0; cc < 8; ++cc) {
            short8 b0 = *(const short8*)(bb + cc * 512);
            short8 b1 = *(const short8*)(bb + 4096 + cc * 512);
#pragma unroll
            for (int m = 0; m < 2; ++m) {
                acc[m][0] = __builtin_amdgcn_mfma_f32_16x16x32_bf16(afr[m][cc], b0, acc[m][0], 0, 0, 0);
                acc[m][1] = __builtin_amdgcn_mfma_f32_16x16x32_bf16(afr[m][cc], b1, acc[m][1], 0, 0, 0);
            }
        }
        int ent0 = (egbase + kt * 2) * 16 + e;
#pragma unroll
        for (int m = 0; m < 2; ++m) {
            int nb = RB + w * 32 + m * 16 + g * 4;
#pragma unroll
            for (int r = 0; r < 4; ++r) {
                if (acc[m][0][r] >= thr[m][r]) {
                    int n = nb + r;
                    int s = atomicAdd(&cnt[n], 1);
                    if (s < SURV_CAP) surv[n * SURV_CAP + s] = ent0;
                }
                if (acc[m][1][r] >= thr[m][r]) {
                    int n = nb + r;
                    int s = atomicAdd(&cnt[n], 1);
                    if (s < SURV_CAP) surv[n * SURV_CAP + s] = ent0 + 16;
                }
            }
        }

#pragma unroll
        for (int j = 0; j < 4; ++j)
            *(uintx4*)(&bt[(kt + 1) & 1][(j * 256 + tid) * 8]) = pf[j];
        __syncthreads();
    }
}

// Exact fp32 refine: replicate u = fl(znorm - fl(2*dot)) argmin with first-index ties.
// One wave per row; one survivor per lane. Serial fmaf order identical to the
// round-1..6 passing kernels, so idx semantics are unchanged.
__global__ __launch_bounds__(256) void k_refine(const float* __restrict__ zin,
                                                const float* __restrict__ ztf,
                                                const float* __restrict__ cb,
                                                const int* __restrict__ surv,
                                                const int* __restrict__ cnt,
                                                int* __restrict__ idxi,
                                                float* __restrict__ idxf) {
    __shared__ float zr[4][256];
    int w = threadIdx.x >> 6, l = threadIdx.x & 63;
    int n = blockIdx.x * 4 + w;
    if (ztf) {
        const float* zrow = ztf + (size_t)n * 256;
#pragma unroll
        for (int i = 0; i < 4; ++i)
            zr[w][l + 64 * i] = zrow[l + 64 * i];          // coalesced
    } else {
        int b = n >> 12, s = n & 4095;
        const float* zb = zin + ((size_t)b << 20) + s;
#pragma unroll
        for (int i = 0; i < 4; ++i)
            zr[w][l + 64 * i] = zb[(size_t)(l + 64 * i) << 12];
    }
    __syncthreads();
    const float* z = zr[w];
    float zn = 0.f;
    for (int c = 0; c < 256; ++c) zn = fmaf(z[c], z[c], zn);

    int m = cnt[n];
    float bu = 3.0e38f;
    int bk = 0x7fffffff;
    if (m >= 1 && m <= SURV_CAP) {
        if (l < m) {
            int k = surv[n * SURV_CAP + l];
            const float* cr = cb + (size_t)k * 256;
            float d = 0.f;
            for (int c = 0; c < 256; c += 4) {
                floatx4 wv = *(const floatx4*)(cr + c);
                d = fmaf(z[c], wv[0], d);
                d = fmaf(z[c + 1], wv[1], d);
                d = fmaf(z[c + 2], wv[2], d);
                d = fmaf(z[c + 3], wv[3], d);
            }
            bu = zn - 2.0f * d;
            bk = k;
        }
    } else {
        // fallback: exact scan of all K (cold: only on survivor-list overflow)
        for (int k = l; k < K_ENT; k += 64) {
            const float* cr = cb + (size_t)k * 256;
            float d = 0.f;
            for (int c = 0; c < 256; c += 4) {
                floatx4 wv = *(const floatx4*)(cr + c);
                d = fmaf(z[c], wv[0], d);
                d = fmaf(z[c + 1], wv[1], d);
                d = fmaf(z[c + 2], wv[2], d);
                d = fmaf(z[c + 3], wv[3], d);
            }
            float u = zn - 2.0f * d;
            if (u < bu) { bu = u; bk = k; }   // ascending k keeps first min
        }
    }
#pragma unroll
    for (int msk = 1; msk < 64; msk <<= 1) {
        float ou = __shfl_xor(bu, msk);
        int   ok = __shfl_xor(bk, msk);
        if (ou < bu || (ou == bu && ok < bk)) { bu = ou; bk = ok; }
    }
    if (l == 0) { idxi[n] = bk; idxf[n] = (float)bk; }
}

// Gather z_q + loss (coalesced codebook reads via LDS transpose), with fused
// last-block loss finalization (device-scope atomics + threadfence).
__global__ __launch_bounds__(256) void k_gather(const float* __restrict__ zin,
                                                const float* __restrict__ cb,
                                                const int* __restrict__ idxi,
                                                float* __restrict__ out,
                                                double* __restrict__ acc,
                                                int* __restrict__ cnt2) {
    __shared__ float tile[64][65];
    __shared__ int lk[64];
    __shared__ float wsum[4];
    int t = threadIdx.x;
    int blk = blockIdx.x;
    int b = blk >> 6;
    int s0 = (blk & 63) << 6;
    int n0 = (b << 12) + s0;
    if (t < 64) lk[t] = idxi[n0 + t];
    __syncthreads();
    int wv = t >> 6, ln = t & 63;
    float ls = 0.f;
#pragma unroll
    for (int ct = 0; ct < 4; ++ct) {
        int c0 = ct << 6;
#pragma unroll
        for (int i = 0; i < 16; ++i) {
            int sl = (wv << 4) + i;
            tile[sl][ln] = cb[(size_t)lk[sl] * 256 + c0 + ln];   // 256 B coalesced
        }
        __syncthreads();
        const float* zb = zin + ((size_t)b << 20);
        float* ob = out + ((size_t)b << 20);
#pragma unroll
        for (int j = 0; j < 16; ++j) {
            int cl = (wv << 4) + j;
            size_t o = (size_t)(c0 + cl) * 4096 + s0 + ln;
            float v = tile[ln][cl];       // stride-65: 2-way bank alias (free)
            float zv = zb[o];
            ob[o] = v;
            float d = v - zv;
            ls = fmaf(d, d, ls);
        }
        __syncthreads();
    }
#pragma unroll
    for (int msk = 1; msk < 64; msk <<= 1) ls += __shfl_xor(ls, msk);
    if (ln == 0) wsum[wv] = ls;
    __syncthreads();
    if (t == 0) {
        float tot = (wsum[0] + wsum[1]) + (wsum[2] + wsum[3]);
        atomicAdd(acc, (double)tot);
        __threadfence();
        int done = atomicAdd(cnt2, 1);
        if (done == (int)gridDim.x - 1) {
            __threadfence();
            double v = atomicAdd(acc, 0.0);   // coherent read after all adds
            out[LOSS_OFF] = (float)(2.0 * v / 8388608.0);
        }
    }
}

extern "C" void kernel_launch(void* const* d_in, const int* in_sizes, int n_in,
                              void* d_out, int out_size, void* d_ws, size_t ws_size,
                              hipStream_t stream) {
    (void)in_sizes; (void)n_in; (void)out_size;
    const float* z  = (const float*)d_in[0];
    const float* cb = (const float*)d_in[1];
    float* out = (float*)d_out;
    char* ws = (char*)d_ws;

    size_t off = 0;
    ushort_t* zsw  = (ushort_t*)(ws + off); off += 16777216;   // bf16 swizzled z
    ushort_t* cbsw = (ushort_t*)(ws + off); off += 4194304;    // bf16 swizzled codebook
    float* ztf = nullptr;
    const size_t ZTF_BYTES = 33554432;                          // fp32 transposed z
    const size_t TAIL = 4194304 + 131072 + 131072 + 64;
    if (ws_size >= off + ZTF_BYTES + TAIL) { ztf = (float*)(ws + off); off += ZTF_BYTES; }
    int* surv = (int*)(ws + off); off += 4194304;
    int* cnt  = (int*)(ws + off); off += 131072;
    int* idxi = (int*)(ws + off); off += 131072;
    double* acc = (double*)(ws + off); off += 8;
    int* cnt2 = (int*)(ws + off);

    k_conv_cb<<<1024, 256, 0, stream>>>(cb, cbsw, cnt, cnt2, acc);
    k_conv_z<<<2048, 256, 0, stream>>>(z, zsw, ztf);
    k_screen<<<1024, 256, 0, stream>>>(zsw, cbsw, surv, cnt);
    k_refine<<<8192, 256, 0, stream>>>(z, ztf, cb, surv, cnt, idxi, out + IDX_OFF);
    k_gather<<<8192 / 16, 256, 0, stream>>>(z, cb, idxi, out, acc, cnt2);
}